// Round 8
// baseline (1970.395 us; speedup 1.0000x reference)
//
#include <hip/hip_runtime.h>
#include <cstdint>
#include <cstddef>

#define BB 4
#define NN 8192
#define NPP 2048
#define NSS 32
#define CINN 128
#define COUTT 256

// ---------------- DPP reduce helpers (VALU-only cross-lane) ----------------
template<int CTRL>
static __device__ __forceinline__ float dppf(float v){
  return __int_as_float(__builtin_amdgcn_update_dpp(0, __float_as_int(v), CTRL, 0xF, 0xF, true));
}
// full-wave (64) max; valid result in lane 63. Values must be >= 0 (true here).
static __device__ __forceinline__ float wave_max63(float v){
  v = fmaxf(v, dppf<0xB1>(v));   // quad_perm xor1
  v = fmaxf(v, dppf<0x4E>(v));   // quad_perm xor2
  v = fmaxf(v, dppf<0x141>(v));  // row_half_mirror (xor7)
  v = fmaxf(v, dppf<0x140>(v));  // row_mirror (xor15)
  v = fmaxf(v, dppf<0x142>(v));  // row_bcast15
  v = fmaxf(v, dppf<0x143>(v));  // row_bcast31
  return v;
}
// reduce within each 4-lane quad; all lanes of the quad get the result
static __device__ __forceinline__ float red4_maxf(float v){
  v = fmaxf(v, dppf<0xB1>(v));   // xor1
  v = fmaxf(v, dppf<0x4E>(v));   // xor2
  return v;
}

// ---------- K1: fused FPS (blocks 0..3) + feats transpose + w transpose ----------
__global__ __launch_bounds__(256)
void k_pre(const float* __restrict__ xyz, const float* __restrict__ feats,
           const float* __restrict__ convw,
           int* __restrict__ fidx, float* __restrict__ featsT, float* __restrict__ wT)
{
  __shared__ union {
    struct {
      float  xs[NN];            // 32768 B
      float  ys[NN];
      float  zs[NN];
      float2 slots[2][4];       // (wm, wi) per wave, parity double-buffer
    } fps;
    float tile[32][65];
  } sm;
  const int tid = threadIdx.x;
  const int blk = blockIdx.x;

  if (blk < BB) {
    // ------------- furthest point sampling, one block (4 waves) per batch -------------
    // 256 thr = 1 wave/SIMD: same issue floor as 512t (640 cyc), minimum barrier population.
    const int b = blk;
    float* xs = sm.fps.xs;
    float* ys = sm.fps.ys;
    float* zs = sm.fps.zs;

    for (int n = tid; n < NN; n += 256){
      const float* p = xyz + ((size_t)b*NN + n)*3;
      xs[n] = p[0]; ys[n] = p[1]; zs[n] = p[2];
    }
    __syncthreads();

    // 32 points per lane (register-resident), r1-identical math
    float px[32], py[32], pz[32], mind[32];
    const int base = tid*32;
    #pragma unroll
    for (int j=0;j<32;++j){
      px[j]=xs[base+j]; py[j]=ys[base+j]; pz[j]=zs[base+j];
      mind[j]=3.0e38f;
    }
    int cur = 0;
    if (tid == 0) fidx[b*NPP] = 0;
    const int lane = tid & 63;
    const int wid  = tid >> 6;    // 0..3

    for (int s = 1; s < NPP; ++s){
      const float cx = xs[cur], cy = ys[cur], cz = zs[cur];
      // two independent 16-long select chains (A = j 0..15, B = j 16..31), merged at end
      float bvA = -1.0f, bvB = -1.0f; int bjA = 0, bjB = 16;
      #pragma unroll
      for (int j=0;j<16;++j){
        // EXACT reference formula class: ((dx*dx)+dy*dy)+dz*dz with fma fusion
        {
          const float dx = px[j]-cx, dy = py[j]-cy, dz = pz[j]-cz;
          const float d2 = fmaf(dz,dz, fmaf(dy,dy, dx*dx));
          const float m  = fminf(mind[j], d2);
          mind[j] = m;
          const bool g = m > bvA;          // strict >: earliest index on tie
          bvA = g ? m : bvA;
          bjA = g ? j : bjA;
        }
        {
          const int j2 = j + 16;
          const float dx = px[j2]-cx, dy = py[j2]-cy, dz = pz[j2]-cz;
          const float d2 = fmaf(dz,dz, fmaf(dy,dy, dx*dx));
          const float m  = fminf(mind[j2], d2);
          mind[j2] = m;
          const bool g = m > bvB;
          bvB = g ? m : bvB;
          bjB = g ? j2 : bjB;
        }
      }
      // merge: strict > prefers A (lower indices) on tie -> first occurrence
      const bool gB = bvB > bvA;
      const float bv = gB ? bvB : bvA;
      const int   bi = base + (gB ? bjB : bjA);

      // wave argmax: DPP value-max, then ballot+ctz for first (lowest-index) match
      float wm = wave_max63(bv);
      wm = __int_as_float(__builtin_amdgcn_readlane(__float_as_int(wm), 63));
      const unsigned long long lm = __ballot(bv == wm);
      const int wl = (int)__builtin_ctzll(lm);          // lane order == index order
      const int wi = __builtin_amdgcn_readlane(bi, wl);

      const int par = s & 1;                  // parity double-buffer -> 1 barrier/step
      if (lane == 0) sm.fps.slots[par][wid] = make_float2(wm, __int_as_float(wi));
      __syncthreads();

      const float2 sv = sm.fps.slots[par][lane & 3];    // replicated per 4-lane quad
      const int ci = __float_as_int(sv.y);
      const float gm = red4_maxf(sv.x);
      const unsigned long long bm = __ballot(sv.x == gm);
      const int ws = (int)__builtin_ctzll(bm);          // lane 0..3 == slot 0..3 (wave order == index order)
      cur = __builtin_amdgcn_readlane(ci, ws);

      if (tid == 0) fidx[b*NPP + s] = cur;
    }
  } else if (blk < BB + 2048) {
    // -------- feats [b][CIN][NN] -> featsT [b][NN][CIN], tile 32x64, 256 thr --------
    const int tb = blk - BB;
    const int b  = tb >> 9;
    const int t  = tb & 511;
    const int r0 = (t & 3) * 32;     // channel
    const int c0 = (t >> 2) * 64;    // point
    const float* in = feats + (size_t)b*CINN*NN;
    float* outp = featsT + (size_t)b*NN*CINN;
    const int tx = tid & 63, ty = tid >> 6;      // ty 0..3
    #pragma unroll
    for (int u=0;u<8;++u) sm.tile[ty + 4*u][tx] = in[(size_t)(r0+ty+4*u)*NN + (c0+tx)];
    __syncthreads();
    const int tx2 = tid & 31, ty2 = tid >> 5;    // ty2 0..7
    #pragma unroll
    for (int u=0;u<8;++u) outp[(size_t)(c0+ty2+8*u)*CINN + (r0+tx2)] = sm.tile[tx2][ty2+8*u];
  } else {
    // -------- conv_w [COUT][CIN] -> wT [CIN][COUT], tile 32x64, 256 thr --------
    const int t  = blk - BB - 2048;
    const int r0 = (t >> 1) * 32;    // o
    const int c0 = (t & 1) * 64;     // c
    const int tx = tid & 63, ty = tid >> 6;
    #pragma unroll
    for (int u=0;u<8;++u) sm.tile[ty+4*u][tx] = convw[(size_t)(r0+ty+4*u)*CINN + (c0+tx)];
    __syncthreads();
    const int tx2 = tid & 31, ty2 = tid >> 5;
    #pragma unroll
    for (int u=0;u<8;++u) wT[(size_t)(c0+ty2+8*u)*COUTT + (r0+tx2)] = sm.tile[tx2][ty2+8*u];
  }
}

// ---------- K2: ball query — one wave per query; 4 chunks (256 pts) per dependent round ----------
__global__ __launch_bounds__(256)
void k_ball(const float* __restrict__ xyz, const int* __restrict__ fidx, int* __restrict__ idxb)
{
  const int lane = threadIdx.x & 63;
  const int gw = blockIdx.x*4 + (threadIdx.x >> 6);   // 0..8191 = b*NP + p
  const int b = gw >> 11;
  const int qi = fidx[gw];
  const float R2F = (float)(0.2 * 0.2);               // exact jax weak-type promotion
  const float* q = xyz + ((size_t)b*NN + qi)*3;
  const float qx = q[0], qy = q[1], qz = q[2];
  const float* Bp = xyz + (size_t)b*NN*3;
  int* outp = idxb + (size_t)gw*NSS;
  int cnt = 0, first = -1;
  for (int base0 = 0; base0 < NN; base0 += 256){
    float d2u[4];
    #pragma unroll
    for (int u=0;u<4;++u){
      const float* P = Bp + (size_t)(base0 + u*64 + lane)*3;
      const float dx = P[0]-qx, dy = P[1]-qy, dz = P[2]-qz;
      d2u[u] = fmaf(dz,dz, fmaf(dy,dy, dx*dx));
    }
    #pragma unroll
    for (int u=0;u<4;++u){
      const bool hit = d2u[u] < R2F;
      const unsigned long long m = __ballot(hit);
      if (first < 0 && m != 0ull) first = base0 + u*64 + (int)__builtin_ctzll(m);
      const int slot = cnt + (int)__popcll(m & ((1ull<<lane)-1ull));
      if (hit && slot < NSS) outp[slot] = base0 + u*64 + lane;
      cnt += (int)__popcll(m);
    }
    if (cnt >= NSS) break;
  }
  if (cnt < NSS){
    const int f = (first >= 0) ? first : 0;           // reference fallback semantics
    if (lane >= cnt && lane < NSS) outp[lane] = f;
  }
}

// ---------- K3: gather + max-pool; half-wave per query; write pooledC[b][c][p] ----------
__global__ __launch_bounds__(256)
void k_pool(const float* __restrict__ featsT, const int* __restrict__ idxb, float* __restrict__ pooledC)
{
  __shared__ int lidx[256];
  const int tid = threadIdx.x;
  const int blk = blockIdx.x;                 // 1024 blocks, 8 queries each
  lidx[tid] = idxb[(size_t)blk*256 + tid];
  __syncthreads();
  const int hw = tid >> 5, l = tid & 31;
  const int q = blk*8 + hw;
  const int b = q >> 11, p = q & (NPP-1);
  const float4* basep = (const float4*)(featsT + (size_t)b*NN*CINN);
  float4 m = make_float4(-3e38f,-3e38f,-3e38f,-3e38f);
  #pragma unroll 8
  for (int s=0;s<NSS;++s){
    const int i = lidx[hw*32 + s];
    const float4 v = basep[(size_t)i*32 + l]; // coalesced 512B row per point
    m.x = fmaxf(m.x, v.x); m.y = fmaxf(m.y, v.y);
    m.z = fmaxf(m.z, v.z); m.w = fmaxf(m.w, v.w);
  }
  float* oc = pooledC + ((size_t)b*CINN + l*4)*NPP + p;
  oc[0] = m.x; oc[NPP] = m.y; oc[2*(size_t)NPP] = m.z; oc[3*(size_t)NPP] = m.w;
}

// ---------- K4: GEMM (wT coalesced, pooledC uniform/scalar) + BN + LeakyReLU ----------
__global__ __launch_bounds__(256)
void k_gemm(const float* __restrict__ pooledC, const float* __restrict__ wT,
            const float* __restrict__ gamma, const float* __restrict__ beta,
            const float* __restrict__ rmean, const float* __restrict__ rvar,
            float* __restrict__ out)
{
  const int o = threadIdx.x;                 // 0..255 = output channel
  const int blk = blockIdx.x;                // 512 blocks
  const int b = blk >> 7;
  const int p0 = (blk & 127) << 4;           // 16 points per block
  const float* pc = pooledC + (size_t)b*CINN*NPP + p0;
  float acc[16];
  #pragma unroll
  for (int i=0;i<16;++i) acc[i]=0.f;
  #pragma unroll 4
  for (int c=0;c<CINN;++c){
    const float wv = wT[c*COUTT + o];                       // coalesced across block
    const float4* pr = (const float4*)(pc + (size_t)c*NPP); // uniform address
    #pragma unroll
    for (int qq=0;qq<4;++qq){
      const float4 pv = pr[qq];
      acc[4*qq+0] = fmaf(wv, pv.x, acc[4*qq+0]);
      acc[4*qq+1] = fmaf(wv, pv.y, acc[4*qq+1]);
      acc[4*qq+2] = fmaf(wv, pv.z, acc[4*qq+2]);
      acc[4*qq+3] = fmaf(wv, pv.w, acc[4*qq+3]);
    }
  }
  const float inv = gamma[o] / sqrtf(rvar[o] + 1e-5f);
  const float sh  = beta[o] - rmean[o]*inv;
  float4* op = (float4*)(out + ((size_t)b*COUTT + o)*NPP + p0);
  #pragma unroll
  for (int qq=0;qq<4;++qq){
    float4 y;
    float t0 = fmaf(acc[4*qq+0], inv, sh);
    float t1 = fmaf(acc[4*qq+1], inv, sh);
    float t2 = fmaf(acc[4*qq+2], inv, sh);
    float t3 = fmaf(acc[4*qq+3], inv, sh);
    y.x = t0 >= 0.f ? t0 : 0.2f*t0;
    y.y = t1 >= 0.f ? t1 : 0.2f*t1;
    y.z = t2 >= 0.f ? t2 : 0.2f*t2;
    y.w = t3 >= 0.f ? t3 : 0.2f*t3;
    op[qq] = y;
  }
}

extern "C" void kernel_launch(void* const* d_in, const int* in_sizes, int n_in,
                              void* d_out, int out_size, void* d_ws, size_t ws_size,
                              hipStream_t stream)
{
  (void)in_sizes; (void)n_in; (void)out_size; (void)ws_size;
  const float* xyz   = (const float*)d_in[0];
  const float* feats = (const float*)d_in[1];
  const float* convw = (const float*)d_in[2];
  const float* gamma = (const float*)d_in[3];
  const float* beta  = (const float*)d_in[4];
  const float* rmean = (const float*)d_in[5];
  const float* rvar  = (const float*)d_in[6];
  float* out = (float*)d_out;

  char* ws = (char*)d_ws;
  float* featsT  = (float*)(ws);                                  // 16,777,216 B
  float* pooledC = (float*)(ws + 16777216);                       //  4,194,304 B
  float* wT      = (float*)(ws + 16777216 + 4194304);             //    131,072 B
  int*   fidx    = (int*)  (ws + 16777216 + 4194304 + 131072);    //     32,768 B
  int*   idxb    = (int*)  (ws + 16777216 + 4194304 + 131072 + 32768); // 1,048,576 B

  k_pre <<<dim3(BB + 2048 + 16), dim3(256), 0, stream>>>(xyz, feats, convw, fidx, featsT, wT);
  k_ball<<<dim3(2048),           dim3(256), 0, stream>>>(xyz, fidx, idxb);
  k_pool<<<dim3(1024),           dim3(256), 0, stream>>>(featsT, idxb, pooledC);
  k_gemm<<<dim3(512),            dim3(256), 0, stream>>>(pooledC, wT, gamma, beta, rmean, rvar, out);
}

// Round 13
// 1666.216 us; speedup vs baseline: 1.1826x; 1.1826x over previous
//
#include <hip/hip_runtime.h>
#include <cstdint>
#include <cstddef>

#define BB 4
#define NN 8192
#define NPP 2048
#define NSS 32
#define CINN 128
#define COUTT 256

// ---------------- DPP reduce helpers (VALU-only cross-lane) ----------------
template<int CTRL>
static __device__ __forceinline__ float dppf(float v){
  return __int_as_float(__builtin_amdgcn_update_dpp(0, __float_as_int(v), CTRL, 0xF, 0xF, true));
}
// full-wave (64) max; valid result in lane 63. Values must be >= 0 (true here).
static __device__ __forceinline__ float wave_max63(float v){
  v = fmaxf(v, dppf<0xB1>(v));   // quad_perm xor1
  v = fmaxf(v, dppf<0x4E>(v));   // quad_perm xor2
  v = fmaxf(v, dppf<0x141>(v));  // row_half_mirror (xor7)
  v = fmaxf(v, dppf<0x140>(v));  // row_mirror (xor15)
  v = fmaxf(v, dppf<0x142>(v));  // row_bcast15
  v = fmaxf(v, dppf<0x143>(v));  // row_bcast31
  return v;
}

// ---------- K1: fused FPS (blocks 0..3) + feats transpose + w transpose ----------
__global__ __launch_bounds__(512)
void k_pre(const float* __restrict__ xyz, const float* __restrict__ feats,
           const float* __restrict__ convw,
           int* __restrict__ fidx, float* __restrict__ featsT, float* __restrict__ wT)
{
  __shared__ union {
    struct {
      float4 xyzw[NN];               // 131072 B: coords packed for one b128 broadcast read
      unsigned long long cell[4];    // u64 key tournament cells, 4-deep ring
    } fps;
    float tile[32][65];
  } sm;
  const int tid = threadIdx.x;
  const int blk = blockIdx.x;

  if (blk < BB) {
    // ---------------- furthest point sampling, one block (8 waves) per batch ----------------
    const int b = blk;
    float4* P4 = sm.fps.xyzw;
    for (int n = tid; n < NN; n += 512){
      const float* p = xyz + ((size_t)b*NN + n)*3;
      P4[n] = make_float4(p[0], p[1], p[2], 0.f);
    }
    if (tid == 0){
      sm.fps.cell[0] = 0ull; sm.fps.cell[1] = 0ull;
      sm.fps.cell[2] = 0ull; sm.fps.cell[3] = 0ull;
      fidx[b*NPP] = 0;
    }
    __syncthreads();

    // 16 points per lane, register-resident (r1-identical inner math)
    float px[16], py[16], pz[16], mind[16];
    const int base = tid*16;
    #pragma unroll
    for (int j=0;j<16;++j){
      const float4 p4 = P4[base+j];
      px[j]=p4.x; py[j]=p4.y; pz[j]=p4.z;
      mind[j]=3.0e38f;
    }
    const int lane = tid & 63;
    const float4 c0 = P4[0];
    float cx=c0.x, cy=c0.y, cz=c0.z;

    for (int s = 1; s < NPP; ++s){
      float bv = -1.0f; int bj = 0;
      #pragma unroll
      for (int j=0;j<16;++j){
        // EXACT reference formula class: ((dx*dx)+dy*dy)+dz*dz with fma fusion
        const float dx = px[j]-cx, dy = py[j]-cy, dz = pz[j]-cz;
        const float d2 = fmaf(dz,dz, fmaf(dy,dy, dx*dx));
        const float m  = fminf(mind[j], d2);
        mind[j] = m;
        const bool g = m > bv;     // strict >: keeps earliest index on tie
        bv = g ? m : bv;
        bj = g ? j : bj;
      }
      const int bi = base + bj;

      // u64 key: monotone in value; low bits (8191-idx) -> tie breaks to SMALLEST index,
      // exactly the reference's first-occurrence argmax (across lanes AND waves).
      const unsigned long long key =
        ((unsigned long long)__float_as_uint(bv) << 16) | (unsigned)(8191 - bi);

      // wave max value, then the max-holding lane(s) enter the block tournament
      float wm = wave_max63(bv);
      wm = __int_as_float(__builtin_amdgcn_readlane(__float_as_int(wm), 63));
      const int cidx = s & 3;
      if (bv == wm) atomicMax(&sm.fps.cell[cidx], key);   // ~1 lane/wave
      __syncthreads();

      const unsigned long long k = sm.fps.cell[cidx];
      const int cur = 8191 - (int)(k & 0xFFFFull);
      // reset the cell used at step s+2: separated from its future atomics by the
      // s+1 barrier, and from its last readers (step s-2) by two barriers. Race-free.
      if (lane == 0) sm.fps.cell[(s + 2) & 3] = 0ull;
      const float4 w4 = P4[cur];                   // one uniform b128 broadcast read
      cx = w4.x; cy = w4.y; cz = w4.z;
      if (tid == 0) fidx[b*NPP + s] = cur;
    }
  } else if (blk < BB + 2048) {
    // -------- feats [b][CIN][NN] -> featsT [b][NN][CIN], tile 32x64 --------
    const int tb = blk - BB;
    const int b  = tb >> 9;
    const int t  = tb & 511;
    const int r0 = (t & 3) * 32;     // channel
    const int c0 = (t >> 2) * 64;    // point
    const float* in = feats + (size_t)b*CINN*NN;
    float* outp = featsT + (size_t)b*NN*CINN;
    const int tx = tid & 63, ty = tid >> 6;
    #pragma unroll
    for (int u=0;u<4;++u) sm.tile[ty + 8*u][tx] = in[(size_t)(r0+ty+8*u)*NN + (c0+tx)];
    __syncthreads();
    const int tx2 = tid & 31, ty2 = tid >> 5;
    #pragma unroll
    for (int u=0;u<4;++u) outp[(size_t)(c0+ty2+16*u)*CINN + (r0+tx2)] = sm.tile[tx2][ty2+16*u];
  } else {
    // -------- conv_w [COUT][CIN] -> wT [CIN][COUT], tile 32x64 --------
    const int t  = blk - BB - 2048;
    const int r0 = (t >> 1) * 32;    // o
    const int c0 = (t & 1) * 64;     // c
    const int tx = tid & 63, ty = tid >> 6;
    #pragma unroll
    for (int u=0;u<4;++u) sm.tile[ty+8*u][tx] = convw[(size_t)(r0+ty+8*u)*CINN + (c0+tx)];
    __syncthreads();
    const int tx2 = tid & 31, ty2 = tid >> 5;
    #pragma unroll
    for (int u=0;u<4;++u) wT[(size_t)(c0+ty2+16*u)*COUTT + (r0+tx2)] = sm.tile[tx2][ty2+16*u];
  }
}

// ---------- K2: fused ball query + gather/max-pool (4 queries per 256-thr block) ----------
__global__ __launch_bounds__(256)
void k_ballpool(const float* __restrict__ xyz, const int* __restrict__ fidx,
                const float* __restrict__ featsT, float* __restrict__ pooledC)
{
  __shared__ int lidx[4*NSS];
  const int tid = threadIdx.x;
  const int lane = tid & 63;
  const int w = tid >> 6;                       // 0..3
  const int gw = blockIdx.x*4 + w;              // b*NP + p
  const int b = gw >> 11;

  // ---- ball phase (one wave per query; 4 chunks per dependent round) ----
  {
    const int qi = fidx[gw];
    const float R2F = (float)(0.2 * 0.2);       // exact jax weak-type promotion
    const float* q = xyz + ((size_t)b*NN + qi)*3;
    const float qx = q[0], qy = q[1], qz = q[2];
    const float* Bp = xyz + (size_t)b*NN*3;
    int cnt = 0, first = -1;
    for (int base0 = 0; base0 < NN; base0 += 256){
      float d2u[4];
      #pragma unroll
      for (int u=0;u<4;++u){
        const float* P = Bp + (size_t)(base0 + u*64 + lane)*3;
        const float dx = P[0]-qx, dy = P[1]-qy, dz = P[2]-qz;
        d2u[u] = fmaf(dz,dz, fmaf(dy,dy, dx*dx));
      }
      #pragma unroll
      for (int u=0;u<4;++u){
        const bool hit = d2u[u] < R2F;
        const unsigned long long m = __ballot(hit);
        if (first < 0 && m != 0ull) first = base0 + u*64 + (int)__builtin_ctzll(m);
        const int slot = cnt + (int)__popcll(m & ((1ull<<lane)-1ull));
        if (hit && slot < NSS) lidx[w*NSS + slot] = base0 + u*64 + lane;
        cnt += (int)__popcll(m);
      }
      if (cnt >= NSS) break;
    }
    if (cnt < NSS){
      const int f = (first >= 0) ? first : 0;   // reference fallback semantics
      if (lane >= cnt && lane < NSS) lidx[w*NSS + lane] = f;
    }
  }
  __syncthreads();

  // ---- pool phase: full wave per query; halves take even/odd samples, merge at end ----
  const int c4 = lane & 31;                     // float4-channel 0..31 (128 channels)
  const int sh = lane >> 5;                     // 0: even samples, 1: odd samples
  const float4* basep = (const float4*)(featsT + (size_t)b*NN*CINN);
  float4 m = make_float4(-3e38f,-3e38f,-3e38f,-3e38f);
  #pragma unroll 8
  for (int t=0;t<16;++t){
    const int i = lidx[w*NSS + 2*t + sh];
    const float4 v = basep[(size_t)i*32 + c4];  // coalesced 512B row per point
    m.x = fmaxf(m.x, v.x); m.y = fmaxf(m.y, v.y);
    m.z = fmaxf(m.z, v.z); m.w = fmaxf(m.w, v.w);
  }
  // merge even/odd halves (max is exact under reordering)
  m.x = fmaxf(m.x, __shfl_xor(m.x, 32, 64));
  m.y = fmaxf(m.y, __shfl_xor(m.y, 32, 64));
  m.z = fmaxf(m.z, __shfl_xor(m.z, 32, 64));
  m.w = fmaxf(m.w, __shfl_xor(m.w, 32, 64));
  if (sh == 0){
    const int p = gw & (NPP-1);
    float* oc = pooledC + ((size_t)b*CINN + c4*4)*NPP + p;
    oc[0] = m.x; oc[NPP] = m.y; oc[2*(size_t)NPP] = m.z; oc[3*(size_t)NPP] = m.w;
  }
}

// ---------- K3: GEMM (wT coalesced, pooledC uniform/scalar) + BN + LeakyReLU ----------
__global__ __launch_bounds__(256)
void k_gemm(const float* __restrict__ pooledC, const float* __restrict__ wT,
            const float* __restrict__ gamma, const float* __restrict__ beta,
            const float* __restrict__ rmean, const float* __restrict__ rvar,
            float* __restrict__ out)
{
  const int o = threadIdx.x;                 // 0..255 = output channel
  const int blk = blockIdx.x;                // 512 blocks
  const int b = blk >> 7;
  const int p0 = (blk & 127) << 4;           // 16 points per block
  const float* pc = pooledC + (size_t)b*CINN*NPP + p0;
  float acc[16];
  #pragma unroll
  for (int i=0;i<16;++i) acc[i]=0.f;
  #pragma unroll 4
  for (int c=0;c<CINN;++c){
    const float wv = wT[c*COUTT + o];                       // coalesced across block
    const float4* pr = (const float4*)(pc + (size_t)c*NPP); // uniform address
    #pragma unroll
    for (int qq=0;qq<4;++qq){
      const float4 pv = pr[qq];
      acc[4*qq+0] = fmaf(wv, pv.x, acc[4*qq+0]);
      acc[4*qq+1] = fmaf(wv, pv.y, acc[4*qq+1]);
      acc[4*qq+2] = fmaf(wv, pv.z, acc[4*qq+2]);
      acc[4*qq+3] = fmaf(wv, pv.w, acc[4*qq+3]);
    }
  }
  const float inv = gamma[o] / sqrtf(rvar[o] + 1e-5f);
  const float sh  = beta[o] - rmean[o]*inv;
  float4* op = (float4*)(out + ((size_t)b*COUTT + o)*NPP + p0);
  #pragma unroll
  for (int qq=0;qq<4;++qq){
    float4 y;
    float t0 = fmaf(acc[4*qq+0], inv, sh);
    float t1 = fmaf(acc[4*qq+1], inv, sh);
    float t2 = fmaf(acc[4*qq+2], inv, sh);
    float t3 = fmaf(acc[4*qq+3], inv, sh);
    y.x = t0 >= 0.f ? t0 : 0.2f*t0;
    y.y = t1 >= 0.f ? t1 : 0.2f*t1;
    y.z = t2 >= 0.f ? t2 : 0.2f*t2;
    y.w = t3 >= 0.f ? t3 : 0.2f*t3;
    op[qq] = y;
  }
}

extern "C" void kernel_launch(void* const* d_in, const int* in_sizes, int n_in,
                              void* d_out, int out_size, void* d_ws, size_t ws_size,
                              hipStream_t stream)
{
  (void)in_sizes; (void)n_in; (void)out_size; (void)ws_size;
  const float* xyz   = (const float*)d_in[0];
  const float* feats = (const float*)d_in[1];
  const float* convw = (const float*)d_in[2];
  const float* gamma = (const float*)d_in[3];
  const float* beta  = (const float*)d_in[4];
  const float* rmean = (const float*)d_in[5];
  const float* rvar  = (const float*)d_in[6];
  float* out = (float*)d_out;

  char* ws = (char*)d_ws;
  float* featsT  = (float*)(ws);                                  // 16,777,216 B
  float* pooledC = (float*)(ws + 16777216);                       //  4,194,304 B
  float* wT      = (float*)(ws + 16777216 + 4194304);             //    131,072 B
  int*   fidx    = (int*)  (ws + 16777216 + 4194304 + 131072);    //     32,768 B

  k_pre     <<<dim3(BB + 2048 + 16), dim3(512), 0, stream>>>(xyz, feats, convw, fidx, featsT, wT);
  k_ballpool<<<dim3(2048),           dim3(256), 0, stream>>>(xyz, fidx, featsT, pooledC);
  k_gemm    <<<dim3(512),            dim3(256), 0, stream>>>(pooledC, wT, gamma, beta, rmean, rvar, out);
}